// Round 6
// baseline (102.786 us; speedup 1.0000x reference)
//
#include <hip/hip_runtime.h>

// LSNet collapse: final mask x == 0 everywhere (argmax over identical negsum9
// channels == 0), so the network reduces to:
//   c2  = sum(inp) / 4194304
//   out = tanh( conv3x3x3( c2^2 - 2*c2*inp , c1_w, zero-padded operand ) )
// (biases cancel; out-of-bounds taps contribute exactly 0).
//
// Stencil strategy: z-walk. Each thread owns an x-quad (4 floats) at one h row
// and marches 8 consecutive d planes. Each plane's 3 h-rows are loaded ONCE
// and contribute to 3 rotating output accumulators (slices dz=+1/0/-1).
//
// R5 bugfix: accumulations are guarded by the target-output validity range —
// at off=0/1 the C2/C1 contributions target outputs of the PREVIOUS chunk and
// must not pollute the rotating slots (caused absmax 0.9 in R5).

#define NVOX (2 * 128 * 128 * 128)   // 4194304
#define CH 8                          // d-planes per thread walk

__global__ __launch_bounds__(256) void k_reduce_partial(const float* __restrict__ inp,
                                                        float* __restrict__ partial) {
    int tid = blockIdx.x * 256 + threadIdx.x;           // 0 .. 262143
    const float4* in4 = (const float4*)inp;
    float s = 0.f;
#pragma unroll
    for (int i = 0; i < 4; ++i) {
        float4 v = in4[tid + i * 262144];
        s += (v.x + v.y) + (v.z + v.w);
    }
#pragma unroll
    for (int off = 32; off > 0; off >>= 1) s += __shfl_down(s, off, 64);
    __shared__ float ws[4];
    int lane = threadIdx.x & 63;
    int wid  = threadIdx.x >> 6;
    if (lane == 0) ws[wid] = s;
    __syncthreads();
    if (threadIdx.x == 0) partial[blockIdx.x] = (ws[0] + ws[1]) + (ws[2] + ws[3]);
}

__device__ __forceinline__ float fast_tanh(float x) {
    float e = __expf(2.f * x);
    return 1.f - 2.f * __builtin_amdgcn_rcpf(e + 1.f);
}

// block = (32, 8): tx = x-quad, ty = h row.  grid = (1, 16, 32):
// y: 16 h-tiles of 8; z = n*16 + chunk (chunk of CH=8 d-planes).
__global__ __launch_bounds__(256) void k_stencil(const float* __restrict__ inp,
                                                 const float* __restrict__ w27,
                                                 const float* __restrict__ partial,
                                                 float* __restrict__ out) {
    const int tx   = threadIdx.x;                 // 0..31
    const int ty   = threadIdx.y;                 // 0..7
    const int lin  = ty * 32 + tx;
    const int lane = lin & 63;

    // ---- fold final reduction: sum 1024 partials (4 KB, L2-hot) ----
    __shared__ float ws[4];
    __shared__ float c2sh;
    {
        const float4* p4 = (const float4*)partial;   // 256 float4
        float4 v = p4[lin];
        float s = (v.x + v.y) + (v.z + v.w);
#pragma unroll
        for (int off = 32; off > 0; off >>= 1) s += __shfl_down(s, off, 64);
        if (lane == 0) ws[lin >> 6] = s;
        __syncthreads();
        if (lin == 0) c2sh = ((ws[0] + ws[1]) + (ws[2] + ws[3])) / (float)NVOX;
        __syncthreads();
    }
    const float c2   = c2sh;
    const float c2sq = c2 * c2;
    const float m2c2 = -2.f * c2;

    float wr[27];
#pragma unroll
    for (int i = 0; i < 27; ++i) wr[i] = w27[i];

    const int h     = blockIdx.y * 8 + ty;        // 0..127
    const int zslot = blockIdx.z;                 // 0..31
    const int n     = zslot >> 4;                 // 0..1
    const int d0    = (zslot & 15) * CH;          // 0,8,..,120
    const float* vol = inp + ((size_t)n << 21);   // n * 128^3
    float*      ovol = out + ((size_t)n << 21);

    // rotating accumulators: slot((m+2)%3) holds output d0+m
    float4 a0 = {0,0,0,0}, a1 = {0,0,0,0}, a2 = {0,0,0,0};

#pragma unroll
    for (int off = 0; off < CH + 2; ++off) {
        const int p = d0 - 1 + off;               // plane index
        float4 C0 = {0,0,0,0}, C1 = {0,0,0,0}, C2 = {0,0,0,0};
        if ((unsigned)p < 128u) {
#pragma unroll
            for (int j = 0; j < 3; ++j) {         // h-1, h, h+1
                const int h2 = h + j - 1;
                if ((unsigned)h2 >= 128u) continue;
                const float4* row = (const float4*)(vol + ((size_t)p << 14) + (h2 << 7));
                float4 v = row[tx];
                float4 t;
                t.x = fmaf(m2c2, v.x, c2sq);
                t.y = fmaf(m2c2, v.y, c2sq);
                t.z = fmaf(m2c2, v.z, c2sq);
                t.w = fmaf(m2c2, v.w, c2sq);
                float tL = __shfl(t.w, (lane - 1) & 63, 64);
                float tR = __shfl(t.x, (lane + 1) & 63, 64);
                if (tx == 0)  tL = 0.f;
                if (tx == 31) tR = 0.f;
#pragma unroll
                for (int s = 0; s < 3; ++s) {     // slice dz index
                    const int r = s * 9 + j * 3;
                    const float w0 = wr[r], w1 = wr[r + 1], w2 = wr[r + 2];
                    float4& C = (s == 0) ? C0 : (s == 1) ? C1 : C2;
                    C.x = fmaf(w0, tL,  fmaf(w1, t.x, fmaf(w2, t.y, C.x)));
                    C.y = fmaf(w0, t.x, fmaf(w1, t.y, fmaf(w2, t.z, C.y)));
                    C.z = fmaf(w0, t.y, fmaf(w1, t.z, fmaf(w2, t.w, C.z)));
                    C.w = fmaf(w0, t.z, fmaf(w1, t.w, fmaf(w2, tR,  C.w)));
                }
            }
            // plane p contributes: out(p-1)+=C2, out(p)+=C1, out(p+1)+=C0
            // Guard each by its target's membership in THIS chunk:
            //   C2 -> m = off-2 in [0,CH-1]  <=>  2 <= off <= CH+1
            //   C1 -> m = off-1 in [0,CH-1]  <=>  1 <= off <= CH
            //   C0 -> m = off   in [0,CH-1]  <=>  0 <= off <= CH-1
            {
                const int s2 = (off + 3) % 3;     // slot for m=off-2
                const int s1 = (off + 1) % 3;     // slot for m=off-1
                const int s0 = (off + 2) % 3;     // slot for m=off
                float4& A2 = (s2 == 0) ? a0 : (s2 == 1) ? a1 : a2;
                float4& A1 = (s1 == 0) ? a0 : (s1 == 1) ? a1 : a2;
                float4& A0 = (s0 == 0) ? a0 : (s0 == 1) ? a1 : a2;
                if (off >= 2) {
                    A2.x += C2.x; A2.y += C2.y; A2.z += C2.z; A2.w += C2.w;
                }
                if (off >= 1 && off <= CH) {
                    A1.x += C1.x; A1.y += C1.y; A1.z += C1.z; A1.w += C1.w;
                }
                if (off <= CH - 1) {
                    A0.x += C0.x; A0.y += C0.y; A0.z += C0.z; A0.w += C0.w;
                }
            }
        }
        // output m = off-2 is complete now (all contributing planes processed)
        if (off >= 2) {
            const int m  = off - 2;               // 0..CH-1
            const int sd = off % 3;               // slot((m+2)%3)
            float4& A = (sd == 0) ? a0 : (sd == 1) ? a1 : a2;
            float4 o;
            o.x = fast_tanh(A.x);
            o.y = fast_tanh(A.y);
            o.z = fast_tanh(A.z);
            o.w = fast_tanh(A.w);
            float4* orow = (float4*)(ovol + ((size_t)(d0 + m) << 14) + (h << 7));
            orow[tx] = o;
            A.x = 0.f; A.y = 0.f; A.z = 0.f; A.w = 0.f;   // recycle for m=off+1
        }
    }
}

extern "C" void kernel_launch(void* const* d_in, const int* in_sizes, int n_in,
                              void* d_out, int out_size, void* d_ws, size_t ws_size,
                              hipStream_t stream) {
    // inputs: 0=x, 1=inp, 2=conv_w, 3=conv_b, 4=bn_g, 5=bn_b, 6=c1_w, 7=c1_b
    const float* inp = (const float*)d_in[1];
    const float* c1w = (const float*)d_in[6];
    float* out = (float*)d_out;

    float* partial = (float*)d_ws;   // 1024 floats

    hipLaunchKernelGGL(k_reduce_partial, dim3(1024), dim3(256), 0, stream, inp, partial);

    dim3 blk(32, 8, 1);
    dim3 grd(1, 16, 32);
    hipLaunchKernelGGL(k_stencil, grd, blk, 0, stream, inp, c1w, partial, out);
}

// Round 8
// 97.022 us; speedup vs baseline: 1.0594x; 1.0594x over previous
//
#include <hip/hip_runtime.h>

// LSNet collapse: final mask x == 0 everywhere (argmax over identical negsum9
// channels == 0), so the network reduces to:
//   c2  = sum(inp) / 4194304
//   out = tanh( conv3x3x3( c2^2 - 2*c2*inp , c1_w, zero-padded operand ) )
// (biases cancel; out-of-bounds taps contribute exactly 0).
//
// R8: same as R7 (high-parallelism: 4096 blocks, 1 output-quad/thread, all 9
// row-loads issued upfront branch-free), with the nontemporal store done via a
// native clang ext_vector type (HIP float4* is a class type the builtin rejects).

#define NVOX (2 * 128 * 128 * 128)   // 4194304

typedef float nfloat4 __attribute__((ext_vector_type(4)));

__global__ __launch_bounds__(256) void k_reduce_partial(const float* __restrict__ inp,
                                                        float* __restrict__ partial) {
    int tid = blockIdx.x * 256 + threadIdx.x;           // 0 .. 262143
    const float4* in4 = (const float4*)inp;
    float s = 0.f;
#pragma unroll
    for (int i = 0; i < 4; ++i) {
        float4 v = in4[tid + i * 262144];
        s += (v.x + v.y) + (v.z + v.w);
    }
#pragma unroll
    for (int off = 32; off > 0; off >>= 1) s += __shfl_down(s, off, 64);
    __shared__ float ws[4];
    int lane = threadIdx.x & 63;
    int wid  = threadIdx.x >> 6;
    if (lane == 0) ws[wid] = s;
    __syncthreads();
    if (threadIdx.x == 0) partial[blockIdx.x] = (ws[0] + ws[1]) + (ws[2] + ws[3]);
}

__device__ __forceinline__ float fast_tanh(float x) {
    float e = __expf(2.f * x);
    return 1.f - 2.f * __builtin_amdgcn_rcpf(e + 1.f);
}

// block = (32, 8): tx = x-quad, ty = h row.  grid = (1, 16, 256):
// y: 16 h-tiles of 8; z = n*128 + d plane.
__global__ __launch_bounds__(256) void k_stencil(const float* __restrict__ inp,
                                                 const float* __restrict__ w27,
                                                 const float* __restrict__ partial,
                                                 float* __restrict__ out) {
    const int tx   = threadIdx.x;                 // 0..31
    const int ty   = threadIdx.y;                 // 0..7
    const int lin  = ty * 32 + tx;
    const int lane = lin & 63;

    // ---- fold final reduction: sum 1024 partials (4 KB, L2-hot) ----
    __shared__ float ws[4];
    __shared__ float c2sh;
    {
        const float4* p4 = (const float4*)partial;   // 256 float4
        float4 v = p4[lin];
        float s = (v.x + v.y) + (v.z + v.w);
#pragma unroll
        for (int off = 32; off > 0; off >>= 1) s += __shfl_down(s, off, 64);
        if (lane == 0) ws[lin >> 6] = s;
        __syncthreads();
        if (lin == 0) c2sh = ((ws[0] + ws[1]) + (ws[2] + ws[3])) / (float)NVOX;
        __syncthreads();
    }
    const float c2   = c2sh;
    const float c2sq = c2 * c2;
    const float m2c2 = -2.f * c2;

    float wr[27];
#pragma unroll
    for (int i = 0; i < 27; ++i) wr[i] = w27[i];

    const int h  = blockIdx.y * 8 + ty;           // 0..127
    const int nd = blockIdx.z;                    // global plane, 0..255
    const int d  = nd & 127;

    // ---- issue all 9 row loads upfront, branch-free ----
    float4 v[9];
    float  msk[9];
#pragma unroll
    for (int dz = -1; dz <= 1; ++dz) {
        const bool vz = (unsigned)(d + dz) < 128u;
        const int  pz = vz ? (nd + dz) : nd;      // clamped plane
#pragma unroll
        for (int dy = -1; dy <= 1; ++dy) {
            const int  h2 = h + dy;
            const bool vy = (unsigned)h2 < 128u;
            const int  hc = vy ? h2 : h;          // clamped row
            const int  idx = (dz + 1) * 3 + (dy + 1);
            msk[idx] = (vz && vy) ? 1.f : 0.f;
            v[idx] = ((const float4*)(inp + ((size_t)pz << 14) + (hc << 7)))[tx];
        }
    }

    // ---- transform, mask, gather x-halo, accumulate ----
    float4 acc = {0.f, 0.f, 0.f, 0.f};
#pragma unroll
    for (int idx = 0; idx < 9; ++idx) {
        const float m = msk[idx];
        float4 t;
        t.x = m * fmaf(m2c2, v[idx].x, c2sq);
        t.y = m * fmaf(m2c2, v[idx].y, c2sq);
        t.z = m * fmaf(m2c2, v[idx].z, c2sq);
        t.w = m * fmaf(m2c2, v[idx].w, c2sq);
        float tL = __shfl(t.w, (lane - 1) & 63, 64);
        float tR = __shfl(t.x, (lane + 1) & 63, 64);
        if (tx == 0)  tL = 0.f;
        if (tx == 31) tR = 0.f;
        const int r = idx * 3;                    // (dz+1)*9 + (dy+1)*3
        const float w0 = wr[r], w1 = wr[r + 1], w2 = wr[r + 2];
        acc.x = fmaf(w0, tL,  fmaf(w1, t.x, fmaf(w2, t.y, acc.x)));
        acc.y = fmaf(w0, t.x, fmaf(w1, t.y, fmaf(w2, t.z, acc.y)));
        acc.z = fmaf(w0, t.y, fmaf(w1, t.z, fmaf(w2, t.w, acc.z)));
        acc.w = fmaf(w0, t.z, fmaf(w1, t.w, fmaf(w2, tR,  acc.w)));
    }

    nfloat4 o;
    o.x = fast_tanh(acc.x);
    o.y = fast_tanh(acc.y);
    o.z = fast_tanh(acc.z);
    o.w = fast_tanh(acc.w);
    nfloat4* out4 = reinterpret_cast<nfloat4*>(out + ((size_t)nd << 14) + (h << 7));
    __builtin_nontemporal_store(o, out4 + tx);    // streamed; don't pollute L2
}

extern "C" void kernel_launch(void* const* d_in, const int* in_sizes, int n_in,
                              void* d_out, int out_size, void* d_ws, size_t ws_size,
                              hipStream_t stream) {
    // inputs: 0=x, 1=inp, 2=conv_w, 3=conv_b, 4=bn_g, 5=bn_b, 6=c1_w, 7=c1_b
    const float* inp = (const float*)d_in[1];
    const float* c1w = (const float*)d_in[6];
    float* out = (float*)d_out;

    float* partial = (float*)d_ws;   // 1024 floats

    hipLaunchKernelGGL(k_reduce_partial, dim3(1024), dim3(256), 0, stream, inp, partial);

    dim3 blk(32, 8, 1);
    dim3 grd(1, 16, 256);
    hipLaunchKernelGGL(k_stencil, grd, blk, 0, stream, inp, c1w, partial, out);
}